// Round 10
// baseline (226.087 us; speedup 1.0000x reference)
//
#include <hip/hip_runtime.h>
#include <hip/hip_bf16.h>
#include <math.h>

#define D_MODEL 1024
#define NHEADS  16
#define DK      64
#define SEQ     2048
#define BATCH   2
#define QTILE   64

typedef __attribute__((ext_vector_type(8)))  short  short8;
typedef __attribute__((ext_vector_type(8)))  unsigned short ushort8;
typedef __attribute__((ext_vector_type(4)))  float  floatx4;
typedef __attribute__((ext_vector_type(16))) float  floatx16;

__device__ __forceinline__ unsigned short f2bf(float f) {      // RNE
    union { float f; unsigned int u; } v; v.f = f;
    unsigned int u = v.u;
    return (unsigned short)((u + 0x7FFFu + ((u >> 16) & 1u)) >> 16);
}
__device__ __forceinline__ float bf2f(unsigned short u) {
    union { unsigned int u; float f; } v; v.u = ((unsigned int)u) << 16;
    return v.f;
}
__device__ __forceinline__ unsigned int fau(float f) {
    union { float f; unsigned int u; } v; v.f = f; return v.u;
}

// async global->LDS, 16B per lane. LDS dest = wave-uniform base + lane*16.
__device__ __forceinline__ void gload_lds16(const unsigned short* g, unsigned short* l) {
    __builtin_amdgcn_global_load_lds((__attribute__((address_space(1))) const void*)g,
                                     (__attribute__((address_space(3))) void*)l,
                                     16, 0, 0);
}

// ---------------- fused fp32 -> bf16 pack of x, w_qkv, w_out ----------------
#define X8 ((BATCH * SEQ * D_MODEL) / 8)
#define W8 ((3 * D_MODEL * D_MODEL) / 8)
#define O8 ((D_MODEL * D_MODEL) / 8)
__global__ __launch_bounds__(256) void pack_all(const float* __restrict__ x,
                                                const float* __restrict__ wq,
                                                const float* __restrict__ wo,
                                                unsigned short* __restrict__ xb,
                                                unsigned short* __restrict__ wqb,
                                                unsigned short* __restrict__ wob) {
    const int t = blockIdx.x * blockDim.x + threadIdx.x;
    const float* src; unsigned short* dst; int idx;
    if (t < X8)           { src = x;  dst = xb;  idx = t; }
    else if (t < X8 + W8) { src = wq; dst = wqb; idx = t - X8; }
    else if (t < X8 + W8 + O8) { src = wo; dst = wob; idx = t - X8 - W8; }
    else return;
    const float4 a = ((const float4*)src)[2 * idx];
    const float4 b = ((const float4*)src)[2 * idx + 1];
    short8 o;
    o[0] = (short)f2bf(a.x); o[1] = (short)f2bf(a.y);
    o[2] = (short)f2bf(a.z); o[3] = (short)f2bf(a.w);
    o[4] = (short)f2bf(b.x); o[5] = (short)f2bf(b.y);
    o[6] = (short)f2bf(b.z); o[7] = (short)f2bf(b.w);
    ((short8*)dst)[idx] = o;
}

// ---------------- bf16 MFMA GEMM (m97 structure): C = A @ B^T (+bias) ----------------
template <int TM, typename OUT_T>
__global__ __launch_bounds__(256) void gemm_bf16(const unsigned short* __restrict__ A,
                                                 const unsigned short* __restrict__ B,
                                                 const float* __restrict__ bias,
                                                 OUT_T* __restrict__ C,
                                                 int M, int N, int K) {
    constexpr int NAF = TM / 32;               // A-frags per wave
    __shared__ __align__(16) unsigned short As[TM][32];
    __shared__ __align__(16) unsigned short Bs[128][32];

    const int tid  = threadIdx.x;
    const int wave = tid >> 6;
    const int lane = tid & 63;
    const int quad = lane >> 4;
    const int lcol = lane & 15;
    const int wr   = (wave >> 1) * (TM / 2);
    const int wc   = (wave & 1) * 64;
    const int tm   = blockIdx.y * TM;
    const int tn   = blockIdx.x * 128;

    const int srowA = wave * (TM / 4) + (lane >> 2);
    const int srowB = wave * 32 + (lane >> 2);
    const int scol  = (lane & 3) * 8;
    const unsigned short* gB0 = B + (size_t)(tn + srowB) * K + scol;
    const unsigned short* gB1 = gB0 + (size_t)16 * K;
    unsigned short* lB0 = &Bs[wave * 32][0];
    unsigned short* lB1 = &Bs[wave * 32 + 16][0];

    floatx4 acc[NAF][4];
#pragma unroll
    for (int i = 0; i < NAF; ++i)
#pragma unroll
        for (int j = 0; j < 4; ++j) acc[i][j] = (floatx4){0.f, 0.f, 0.f, 0.f};

    for (int k0 = 0; k0 < K; k0 += 32) {
        __syncthreads();
#pragma unroll
        for (int u = 0; u < TM / 64; ++u)
            gload_lds16(A + (size_t)(tm + srowA + u * 16) * K + k0 + scol,
                        &As[wave * (TM / 4) + u * 16][0]);
        gload_lds16(gB0 + k0, lB0);
        gload_lds16(gB1 + k0, lB1);
        __syncthreads();

        short8 af[NAF], bf[4];
#pragma unroll
        for (int i = 0; i < NAF; ++i) af[i] = *(short8*)&As[wr + i * 16 + lcol][quad * 8];
#pragma unroll
        for (int j = 0; j < 4; ++j) bf[j] = *(short8*)&Bs[wc + j * 16 + lcol][quad * 8];
#pragma unroll
        for (int i = 0; i < NAF; ++i)
#pragma unroll
            for (int j = 0; j < 4; ++j)
                acc[i][j] = __builtin_amdgcn_mfma_f32_16x16x32_bf16(af[i], bf[j], acc[i][j], 0, 0, 0);
    }

#pragma unroll
    for (int i = 0; i < NAF; ++i) {
#pragma unroll
        for (int r = 0; r < 4; ++r) {
            const int row = tm + wr + i * 16 + quad * 4 + r;
#pragma unroll
            for (int j = 0; j < 4; ++j) {
                const int col = tn + wc + j * 16 + lcol;
                float v = acc[i][j][r];
                if (bias) v += bias[col];
                if constexpr (sizeof(OUT_T) == 2)
                    C[(size_t)row * N + col] = (OUT_T)f2bf(v);
                else
                    C[(size_t)row * N + col] = (OUT_T)v;
            }
        }
    }
}

// ---------------- fused RoPE pack (Q*0.125*log2e, K) + sigma-permuted V transpose ---
// Key u within each 64-tile is stored at column c(u) = (u&48) | (8*((u>>2)&1) + (u&3)
// + 4*((u>>3)&1)) so PV's A-operand (= S^T C-regs) and B-operand (V) agree on the
// 32x32x16 MFMA k-index mapping.
__global__ __launch_bounds__(256) void rope_vtrans(const unsigned short* __restrict__ qkvb,
                                                   unsigned short* __restrict__ Qb,
                                                   unsigned short* __restrict__ Kb,
                                                   unsigned short* __restrict__ Vtg) {
    const int st = blockIdx.x, h = blockIdx.y, b = blockIdx.z;
    const int tid = threadIdx.x;
    const int s0 = st * 64;

    // ---- RoPE on Q,K ----
    const int i  = tid & 31;
    const int r0 = tid >> 5;                   // 0..7
    const float inv_freq = exp2f(-(2.0f * (float)i / (float)DK) * log2f(50.0f));
    const float QSCALE = 0.125f * 1.44269504f; // 1/sqrt(dk) * log2(e)
#pragma unroll
    for (int pass = 0; pass < 8; ++pass) {
        const int s = s0 + r0 + pass * 8;
        const size_t in_base = ((size_t)(b * SEQ + s)) * (3 * D_MODEL) + h * DK + 2 * i;
        const float q0 = bf2f(qkvb[in_base]),           q1 = bf2f(qkvb[in_base + 1]);
        const float k0 = bf2f(qkvb[in_base + D_MODEL]), k1 = bf2f(qkvb[in_base + D_MODEL + 1]);
        float sn, cs;
        __sincosf((float)s * inv_freq, &sn, &cs);
        const size_t ob = (((size_t)(b * NHEADS + h)) * SEQ + s) * DK + 2 * i;
        const unsigned int qw = (unsigned int)f2bf((q0 * cs - q1 * sn) * QSCALE)
                              | ((unsigned int)f2bf((q1 * cs + q0 * sn) * QSCALE) << 16);
        const unsigned int kw = (unsigned int)f2bf(k0 * cs - k1 * sn)
                              | ((unsigned int)f2bf(k1 * cs + k0 * sn) << 16);
        *(unsigned int*)&Qb[ob] = qw;
        *(unsigned int*)&Kb[ob] = kw;
    }

    // ---- V transpose with sigma column permutation ----
    __shared__ unsigned short Lt[64][65];
    const int r = tid >> 3;                    // 0..31 (key within tile)
    const int c = (tid & 7) * 8;
    const size_t in_row = ((size_t)(b * SEQ + s0 + r)) * (3 * D_MODEL) + 2 * D_MODEL + h * DK + c;
    const ushort8 v0 = *(const ushort8*)&qkvb[in_row];
    const ushort8 v1 = *(const ushort8*)&qkvb[in_row + (size_t)32 * (3 * D_MODEL)];
    const int u0 = r, u1 = r + 32;
    const int kc0 = (u0 & 48) | (8 * ((u0 >> 2) & 1) + (u0 & 3) + 4 * ((u0 >> 3) & 1));
    const int kc1 = (u1 & 48) | (8 * ((u1 >> 2) & 1) + (u1 & 3) + 4 * ((u1 >> 3) & 1));
#pragma unroll
    for (int j = 0; j < 8; ++j) Lt[c + j][kc0] = v0[j];
#pragma unroll
    for (int j = 0; j < 8; ++j) Lt[c + j][kc1] = v1[j];
    __syncthreads();
    const size_t bh = (size_t)(b * NHEADS + h);
    ushort8 o0, o1;
#pragma unroll
    for (int j = 0; j < 8; ++j) { o0[j] = Lt[r][c + j]; o1[j] = Lt[r + 32][c + j]; }
    unsigned short* orow = Vtg + (bh * DK + r) * SEQ + s0 + c;   // r = d-row
    *(ushort8*)orow = o0;
    *(ushort8*)(orow + (size_t)32 * SEQ) = o1;
}

// ---------------- flash attention: 32x32 MFMA, register P, native v_exp ------------
#define LDW 72

__global__ __launch_bounds__(256) void flash_attn(const unsigned short* __restrict__ Qb,
                                                  const unsigned short* __restrict__ Kb,
                                                  const unsigned short* __restrict__ Vtg,
                                                  unsigned short* __restrict__ attnb) {
    const int qt   = blockIdx.x;              // 0..31 (tiles of 64 queries)
    const int h    = blockIdx.y;
    const int b    = blockIdx.z;
    const int tid  = threadIdx.x;
    const int wave = tid >> 6;
    const int lane = tid & 63;
    const int l31  = lane & 31;
    const int lh   = lane >> 5;               // lane half (k-group)
    const int mh   = wave & 1;                // m-half (32 q rows)
    const int kh   = wave >> 1;               // key-half (32 keys)
    const int kb   = kh * 32;

    __shared__ __align__(16) unsigned char smem[2 * 64 * LDW * 2];   // 18432 B
    unsigned short (*Ks)[LDW] = (unsigned short (*)[LDW])smem;               // [key][dk]
    unsigned short (*Vt)[LDW] = (unsigned short (*)[LDW])(smem + 64 * LDW * 2); // [d][perm key]
    // epilogue overlays (Ks/Vt dead):
    float (*Ored)[68] = (float (*)[68])smem;                          // 64*68*4 = 17408
    float* lred = (float*)(smem + 64 * 68 * 4);                       // 256 B

    const size_t bh = (size_t)(b * NHEADS + h);
    const unsigned short* Qg = Qb + (bh * SEQ + (size_t)qt * QTILE) * DK;
    const unsigned short* Kg = Kb + bh * SEQ * DK;
    const unsigned short* Vg = Vtg + bh * (size_t)DK * SEQ;

    // Q as B-operand: B[n=m=lane&31][k=lh*8+j]; frag t covers dk 16t..16t+15
    short8 qf[4];
#pragma unroll
    for (int t = 0; t < 4; ++t)
        qf[t] = *(const short8*)&Qg[(size_t)(mh * 32 + l31) * DK + t * 16 + lh * 8];

    // ones B-frag for l row-sum MFMA
    short8 ones;
#pragma unroll
    for (int j = 0; j < 8; ++j) ones[j] = (short)0x3F80;

    const int strow = tid >> 3;               // 0..31
    const int stcol = (tid & 7) * 8;
    const unsigned short* kg0 = &Kg[(size_t)strow * DK + stcol];
    const unsigned short* kg1 = &Kg[(size_t)(strow + 32) * DK + stcol];
    const unsigned short* vg0 = &Vg[(size_t)strow * SEQ + stcol];
    const unsigned short* vg1 = &Vg[(size_t)(strow + 32) * SEQ + stcol];

    short8 kr0 = *(const short8*)&kg0[0];
    short8 kr1 = *(const short8*)&kg1[0];
    short8 vr0 = *(const short8*)&vg0[0];
    short8 vr1 = *(const short8*)&vg1[0];

    floatx16 oacc[2];
    floatx16 lacc = (floatx16)(0.f);
    oacc[0] = (floatx16)(0.f);
    oacc[1] = (floatx16)(0.f);

    const int diag_kt = qt * QTILE;

    for (int kt = 0; kt < SEQ; kt += 64) {
        __syncthreads();
        *(short8*)&Ks[strow][stcol]      = kr0;
        *(short8*)&Ks[strow + 32][stcol] = kr1;
        *(short8*)&Vt[strow][stcol]      = vr0;
        *(short8*)&Vt[strow + 32][stcol] = vr1;
        __syncthreads();

        const int ktn = (kt + 64 < SEQ) ? kt + 64 : 0;
        kr0 = *(const short8*)&kg0[(size_t)ktn * DK];
        kr1 = *(const short8*)&kg1[(size_t)ktn * DK];
        vr0 = *(const short8*)&vg0[ktn];
        vr1 = *(const short8*)&vg1[ktn];

        // ---- S^T = K Q^T : C[row=key scatter][col=m=lane&31], 4 MFMAs ----
        floatx16 sc = (floatx16)(0.f);
#pragma unroll
        for (int t = 0; t < 4; ++t) {
            const short8 kf = *(short8*)&Ks[kb + l31][t * 16 + lh * 8];
            sc = __builtin_amdgcn_mfma_f32_32x32x16_bf16(kf, qf[t], sc, 0, 0, 0);
        }

        // ---- diagonal mask: only diag tile, only waves with kh==mh ----
        if (kt == diag_kt && kh == mh) {
#pragma unroll
            for (int r = 0; r < 16; ++r) {
                const int key_loc = (r & 3) + 8 * (r >> 2) + 4 * lh;
                if (key_loc == l31) sc[r] = -1e30f;
            }
        }

        // ---- P = exp2(S^T): native v_exp_f32 + v_perm truncation pack -> A-frags ----
        short8 pf0, pf1;
        {
            union { unsigned int u[4]; short8 s8; } a, c;
#pragma unroll
            for (int d = 0; d < 4; ++d) {
                const float e0 = __builtin_amdgcn_exp2f(sc[2 * d]);
                const float e1 = __builtin_amdgcn_exp2f(sc[2 * d + 1]);
                a.u[d] = __builtin_amdgcn_perm(fau(e1), fau(e0), 0x07060302u);
                const float f0 = __builtin_amdgcn_exp2f(sc[8 + 2 * d]);
                const float f1 = __builtin_amdgcn_exp2f(sc[8 + 2 * d + 1]);
                c.u[d] = __builtin_amdgcn_perm(fau(f1), fau(f0), 0x07060302u);
            }
            pf0 = a.s8;
            pf1 = c.s8;
        }

        // ---- l += P @ ones ----
        lacc = __builtin_amdgcn_mfma_f32_32x32x16_bf16(pf0, ones, lacc, 0, 0, 0);
        lacc = __builtin_amdgcn_mfma_f32_32x32x16_bf16(pf1, ones, lacc, 0, 0, 0);

        // ---- O += P V  (V pre-permuted so k-indices align) ----
#pragma unroll
        for (int nd = 0; nd < 2; ++nd) {
            const short8 vfa = *(short8*)&Vt[nd * 32 + l31][kb + lh * 8];        // keys 0..15
            const short8 vfb = *(short8*)&Vt[nd * 32 + l31][kb + 16 + lh * 8];   // keys 16..31
            oacc[nd] = __builtin_amdgcn_mfma_f32_32x32x16_bf16(pf0, vfa, oacc[nd], 0, 0, 0);
            oacc[nd] = __builtin_amdgcn_mfma_f32_32x32x16_bf16(pf1, vfb, oacc[nd], 0, 0, 0);
        }
    }

    // ---- cross-wave (key-half) reduction through LDS overlay ----
    __syncthreads();                          // Ks/Vt dead
    if (kh == 1) {
#pragma unroll
        for (int r = 0; r < 16; ++r) {
            const int m = mh * 32 + (r & 3) + 8 * (r >> 2) + 4 * lh;
            Ored[m][l31]      = oacc[0][r];
            Ored[m][32 + l31] = oacc[1][r];
            if (l31 == 0) lred[m] = lacc[r];
        }
    }
    __syncthreads();
    if (kh == 0) {
        unsigned short* obase = attnb + ((size_t)b * SEQ + (size_t)qt * QTILE) * D_MODEL + h * DK;
#pragma unroll
        for (int r = 0; r < 16; ++r) {
            const int m = mh * 32 + (r & 3) + 8 * (r >> 2) + 4 * lh;
            const float inv = 1.0f / (lacc[r] + lred[m]);
            const float v0 = (oacc[0][r] + Ored[m][l31]) * inv;
            const float v1 = (oacc[1][r] + Ored[m][32 + l31]) * inv;
            obase[(size_t)m * D_MODEL + l31]      = f2bf(v0);
            obase[(size_t)m * D_MODEL + 32 + l31] = f2bf(v1);
        }
    }
}

extern "C" void kernel_launch(void* const* d_in, const int* in_sizes, int n_in,
                              void* d_out, int out_size, void* d_ws, size_t ws_size,
                              hipStream_t stream) {
    const float* x     = (const float*)d_in[0];
    const float* w_qkv = (const float*)d_in[1];
    const float* w_out = (const float*)d_in[2];
    const float* b_out = (const float*)d_in[3];
    float* out = (float*)d_out;

    const int M = BATCH * SEQ;                                   // 4096
    const size_t X_ELEMS    = (size_t)M * D_MODEL;
    const size_t WQKV_ELEMS = (size_t)3 * D_MODEL * D_MODEL;
    const size_t WOUT_ELEMS = (size_t)D_MODEL * D_MODEL;
    const size_t QKV_ELEMS  = (size_t)M * 3 * D_MODEL;
    const size_t HEAD_ELEMS = (size_t)BATCH * NHEADS * SEQ * DK;

    unsigned short* xb    = (unsigned short*)d_ws;
    unsigned short* wqkvb = xb + X_ELEMS;
    unsigned short* woutb = wqkvb + WQKV_ELEMS;
    unsigned short* qkvb  = woutb + WOUT_ELEMS;
    unsigned short* Qb    = qkvb + QKV_ELEMS;
    unsigned short* Kb    = Qb + HEAD_ELEMS;
    unsigned short* Vtg   = Kb + HEAD_ELEMS;                     // [B,H,64,S] sigma-permuted
    unsigned short* attnb = Vtg + HEAD_ELEMS;

    // 0) pack all inputs to bf16
    pack_all<<<(X8 + W8 + O8 + 255) / 256, 256, 0, stream>>>(x, w_qkv, w_out, xb, wqkvb, woutb);

    // 1) qkvb = xb @ wqkvb^T
    {
        dim3 grid(3 * D_MODEL / 128, M / 128);
        gemm_bf16<128, unsigned short><<<grid, 256, 0, stream>>>(xb, wqkvb, nullptr, qkvb,
                                                                 M, 3 * D_MODEL, D_MODEL);
    }
    // 2) RoPE pack + sigma-permuted V transpose
    {
        dim3 grid(SEQ / 64, NHEADS, BATCH);
        rope_vtrans<<<grid, 256, 0, stream>>>(qkvb, Qb, Kb, Vtg);
    }
    // 3) flash attention (32x32 MFMA, register P, native exp)
    {
        dim3 grid(SEQ / QTILE, NHEADS, BATCH);
        flash_attn<<<grid, 256, 0, stream>>>(Qb, Kb, Vtg, attnb);
    }
    // 4) out = attnb @ woutb^T + b_out
    {
        dim3 grid(D_MODEL / 128, M / 64);
        gemm_bf16<64, float><<<grid, 256, 0, stream>>>(attnb, woutb, b_out, out,
                                                       M, D_MODEL, D_MODEL);
    }
}

// Round 11
// 204.971 us; speedup vs baseline: 1.1030x; 1.1030x over previous
//
#include <hip/hip_runtime.h>
#include <hip/hip_bf16.h>
#include <math.h>

#define D_MODEL 1024
#define NHEADS  16
#define DK      64
#define SEQ     2048
#define BATCH   2
#define QTILE   64

typedef __attribute__((ext_vector_type(8)))  short  short8;
typedef __attribute__((ext_vector_type(8)))  unsigned short ushort8;
typedef __attribute__((ext_vector_type(4)))  float  floatx4;
typedef __attribute__((ext_vector_type(16))) float  floatx16;

__device__ __forceinline__ unsigned short f2bf(float f) {      // RNE
    union { float f; unsigned int u; } v; v.f = f;
    unsigned int u = v.u;
    return (unsigned short)((u + 0x7FFFu + ((u >> 16) & 1u)) >> 16);
}
__device__ __forceinline__ float bf2f(unsigned short u) {
    union { unsigned int u; float f; } v; v.u = ((unsigned int)u) << 16;
    return v.f;
}
__device__ __forceinline__ unsigned int fau(float f) {
    union { float f; unsigned int u; } v; v.f = f; return v.u;
}

// async global->LDS, 16B per lane. LDS dest = wave-uniform base + lane*16.
__device__ __forceinline__ void gload_lds16(const unsigned short* g, unsigned short* l) {
    __builtin_amdgcn_global_load_lds((__attribute__((address_space(1))) const void*)g,
                                     (__attribute__((address_space(3))) void*)l,
                                     16, 0, 0);
}

// ---------------- fused fp32 -> bf16 pack of x, w_qkv, w_out ----------------
#define X8 ((BATCH * SEQ * D_MODEL) / 8)
#define W8 ((3 * D_MODEL * D_MODEL) / 8)
#define O8 ((D_MODEL * D_MODEL) / 8)
__global__ __launch_bounds__(256) void pack_all(const float* __restrict__ x,
                                                const float* __restrict__ wq,
                                                const float* __restrict__ wo,
                                                unsigned short* __restrict__ xb,
                                                unsigned short* __restrict__ wqb,
                                                unsigned short* __restrict__ wob) {
    const int t = blockIdx.x * blockDim.x + threadIdx.x;
    const float* src; unsigned short* dst; int idx;
    if (t < X8)           { src = x;  dst = xb;  idx = t; }
    else if (t < X8 + W8) { src = wq; dst = wqb; idx = t - X8; }
    else if (t < X8 + W8 + O8) { src = wo; dst = wob; idx = t - X8 - W8; }
    else return;
    const float4 a = ((const float4*)src)[2 * idx];
    const float4 b = ((const float4*)src)[2 * idx + 1];
    short8 o;
    o[0] = (short)f2bf(a.x); o[1] = (short)f2bf(a.y);
    o[2] = (short)f2bf(a.z); o[3] = (short)f2bf(a.w);
    o[4] = (short)f2bf(b.x); o[5] = (short)f2bf(b.y);
    o[6] = (short)f2bf(b.z); o[7] = (short)f2bf(b.w);
    ((short8*)dst)[idx] = o;
}

// ---------------- bf16 MFMA GEMM (m97 structure): C = A @ B^T (+bias) ----------------
template <int TM, typename OUT_T>
__global__ __launch_bounds__(256) void gemm_bf16(const unsigned short* __restrict__ A,
                                                 const unsigned short* __restrict__ B,
                                                 const float* __restrict__ bias,
                                                 OUT_T* __restrict__ C,
                                                 int M, int N, int K) {
    constexpr int NAF = TM / 32;               // A-frags per wave
    __shared__ __align__(16) unsigned short As[TM][32];
    __shared__ __align__(16) unsigned short Bs[128][32];

    const int tid  = threadIdx.x;
    const int wave = tid >> 6;
    const int lane = tid & 63;
    const int quad = lane >> 4;
    const int lcol = lane & 15;
    const int wr   = (wave >> 1) * (TM / 2);
    const int wc   = (wave & 1) * 64;
    const int tm   = blockIdx.y * TM;
    const int tn   = blockIdx.x * 128;

    const int srowA = wave * (TM / 4) + (lane >> 2);
    const int srowB = wave * 32 + (lane >> 2);
    const int scol  = (lane & 3) * 8;
    const unsigned short* gB0 = B + (size_t)(tn + srowB) * K + scol;
    const unsigned short* gB1 = gB0 + (size_t)16 * K;
    unsigned short* lB0 = &Bs[wave * 32][0];
    unsigned short* lB1 = &Bs[wave * 32 + 16][0];

    floatx4 acc[NAF][4];
#pragma unroll
    for (int i = 0; i < NAF; ++i)
#pragma unroll
        for (int j = 0; j < 4; ++j) acc[i][j] = (floatx4){0.f, 0.f, 0.f, 0.f};

    for (int k0 = 0; k0 < K; k0 += 32) {
        __syncthreads();
#pragma unroll
        for (int u = 0; u < TM / 64; ++u)
            gload_lds16(A + (size_t)(tm + srowA + u * 16) * K + k0 + scol,
                        &As[wave * (TM / 4) + u * 16][0]);
        gload_lds16(gB0 + k0, lB0);
        gload_lds16(gB1 + k0, lB1);
        __syncthreads();

        short8 af[NAF], bf[4];
#pragma unroll
        for (int i = 0; i < NAF; ++i) af[i] = *(short8*)&As[wr + i * 16 + lcol][quad * 8];
#pragma unroll
        for (int j = 0; j < 4; ++j) bf[j] = *(short8*)&Bs[wc + j * 16 + lcol][quad * 8];
#pragma unroll
        for (int i = 0; i < NAF; ++i)
#pragma unroll
            for (int j = 0; j < 4; ++j)
                acc[i][j] = __builtin_amdgcn_mfma_f32_16x16x32_bf16(af[i], bf[j], acc[i][j], 0, 0, 0);
    }

#pragma unroll
    for (int i = 0; i < NAF; ++i) {
#pragma unroll
        for (int r = 0; r < 4; ++r) {
            const int row = tm + wr + i * 16 + quad * 4 + r;
#pragma unroll
            for (int j = 0; j < 4; ++j) {
                const int col = tn + wc + j * 16 + lcol;
                float v = acc[i][j][r];
                if (bias) v += bias[col];
                if constexpr (sizeof(OUT_T) == 2)
                    C[(size_t)row * N + col] = (OUT_T)f2bf(v);
                else
                    C[(size_t)row * N + col] = (OUT_T)v;
            }
        }
    }
}

// ---------------- fused RoPE pack (Q*0.125*log2e, K) + sigma-permuted V transpose ---
// Key u within each 64-tile is stored at column c(u) = (u&48) | (8*((u>>2)&1) + (u&3)
// + 4*((u>>3)&1)) so PV's A-operand (= S^T C-regs) and B-operand (V) agree on the
// 32x32x16 MFMA k-index mapping.
__global__ __launch_bounds__(256) void rope_vtrans(const unsigned short* __restrict__ qkvb,
                                                   unsigned short* __restrict__ Qb,
                                                   unsigned short* __restrict__ Kb,
                                                   unsigned short* __restrict__ Vtg) {
    const int st = blockIdx.x, h = blockIdx.y, b = blockIdx.z;
    const int tid = threadIdx.x;
    const int s0 = st * 64;

    // ---- RoPE on Q,K ----
    const int i  = tid & 31;
    const int r0 = tid >> 5;                   // 0..7
    const float inv_freq = exp2f(-(2.0f * (float)i / (float)DK) * log2f(50.0f));
    const float QSCALE = 0.125f * 1.44269504f; // 1/sqrt(dk) * log2(e)
#pragma unroll
    for (int pass = 0; pass < 8; ++pass) {
        const int s = s0 + r0 + pass * 8;
        const size_t in_base = ((size_t)(b * SEQ + s)) * (3 * D_MODEL) + h * DK + 2 * i;
        const float q0 = bf2f(qkvb[in_base]),           q1 = bf2f(qkvb[in_base + 1]);
        const float k0 = bf2f(qkvb[in_base + D_MODEL]), k1 = bf2f(qkvb[in_base + D_MODEL + 1]);
        float sn, cs;
        __sincosf((float)s * inv_freq, &sn, &cs);
        const size_t ob = (((size_t)(b * NHEADS + h)) * SEQ + s) * DK + 2 * i;
        const unsigned int qw = (unsigned int)f2bf((q0 * cs - q1 * sn) * QSCALE)
                              | ((unsigned int)f2bf((q1 * cs + q0 * sn) * QSCALE) << 16);
        const unsigned int kw = (unsigned int)f2bf(k0 * cs - k1 * sn)
                              | ((unsigned int)f2bf(k1 * cs + k0 * sn) << 16);
        *(unsigned int*)&Qb[ob] = qw;
        *(unsigned int*)&Kb[ob] = kw;
    }

    // ---- V transpose with sigma column permutation ----
    __shared__ unsigned short Lt[64][65];
    const int r = tid >> 3;                    // 0..31 (key within tile)
    const int c = (tid & 7) * 8;
    const size_t in_row = ((size_t)(b * SEQ + s0 + r)) * (3 * D_MODEL) + 2 * D_MODEL + h * DK + c;
    const ushort8 v0 = *(const ushort8*)&qkvb[in_row];
    const ushort8 v1 = *(const ushort8*)&qkvb[in_row + (size_t)32 * (3 * D_MODEL)];
    const int u0 = r, u1 = r + 32;
    const int kc0 = (u0 & 48) | (8 * ((u0 >> 2) & 1) + (u0 & 3) + 4 * ((u0 >> 3) & 1));
    const int kc1 = (u1 & 48) | (8 * ((u1 >> 2) & 1) + (u1 & 3) + 4 * ((u1 >> 3) & 1));
#pragma unroll
    for (int j = 0; j < 8; ++j) Lt[c + j][kc0] = v0[j];
#pragma unroll
    for (int j = 0; j < 8; ++j) Lt[c + j][kc1] = v1[j];
    __syncthreads();
    const size_t bh = (size_t)(b * NHEADS + h);
    ushort8 o0, o1;
#pragma unroll
    for (int j = 0; j < 8; ++j) { o0[j] = Lt[r][c + j]; o1[j] = Lt[r + 32][c + j]; }
    unsigned short* orow = Vtg + (bh * DK + r) * SEQ + s0 + c;   // r = d-row
    *(ushort8*)orow = o0;
    *(ushort8*)(orow + (size_t)32 * SEQ) = o1;
}

// ---------------- flash attention: 32x32 MFMA, register P, scalar-l ----------------
#define LDW 72

__global__ __launch_bounds__(256, 4) void flash_attn(const unsigned short* __restrict__ Qb,
                                                     const unsigned short* __restrict__ Kb,
                                                     const unsigned short* __restrict__ Vtg,
                                                     unsigned short* __restrict__ attnb) {
    const int qt   = blockIdx.x;              // 0..31 (tiles of 64 queries)
    const int h    = blockIdx.y;
    const int b    = blockIdx.z;
    const int tid  = threadIdx.x;
    const int wave = tid >> 6;
    const int lane = tid & 63;
    const int l31  = lane & 31;
    const int lh   = lane >> 5;               // lane half (k-group)
    const int mh   = wave & 1;                // m-half (32 q rows)
    const int kh   = wave >> 1;               // key-half (32 keys)
    const int kb   = kh * 32;

    __shared__ __align__(16) unsigned char smem[2 * 64 * LDW * 2];   // 18432 B
    unsigned short (*Ks)[LDW] = (unsigned short (*)[LDW])smem;               // [key][dk]
    unsigned short (*Vt)[LDW] = (unsigned short (*)[LDW])(smem + 64 * LDW * 2); // [d][perm key]
    // epilogue overlays (Ks/Vt dead):
    float (*Ored)[68] = (float (*)[68])smem;                          // 64*68*4 = 17408
    float* lred0 = (float*)(smem + 64 * 68 * 4);                      // 256 B
    float* lred1 = lred0 + 64;                                        // 256 B

    const size_t bh = (size_t)(b * NHEADS + h);
    const unsigned short* Qg = Qb + (bh * SEQ + (size_t)qt * QTILE) * DK;
    const unsigned short* Kg = Kb + bh * SEQ * DK;
    const unsigned short* Vg = Vtg + bh * (size_t)DK * SEQ;

    // Q as B-operand: B[n=m=lane&31][k=lh*8+j]; frag t covers dk 16t..16t+15
    short8 qf[4];
#pragma unroll
    for (int t = 0; t < 4; ++t)
        qf[t] = *(const short8*)&Qg[(size_t)(mh * 32 + l31) * DK + t * 16 + lh * 8];

    const int strow = tid >> 3;               // 0..31
    const int stcol = (tid & 7) * 8;
    const unsigned short* kg0 = &Kg[(size_t)strow * DK + stcol];
    const unsigned short* kg1 = &Kg[(size_t)(strow + 32) * DK + stcol];
    const unsigned short* vg0 = &Vg[(size_t)strow * SEQ + stcol];
    const unsigned short* vg1 = &Vg[(size_t)(strow + 32) * SEQ + stcol];

    short8 kr0 = *(const short8*)&kg0[0];
    short8 kr1 = *(const short8*)&kg1[0];
    short8 vr0 = *(const short8*)&vg0[0];
    short8 vr1 = *(const short8*)&vg1[0];

    floatx16 oacc[2];
    oacc[0] = (floatx16)(0.f);
    oacc[1] = (floatx16)(0.f);
    float lp = 0.f;                           // scalar l partial: query m = mh*32+l31

    const int diag_kt = qt * QTILE;

    for (int kt = 0; kt < SEQ; kt += 64) {
        __syncthreads();
        *(short8*)&Ks[strow][stcol]      = kr0;
        *(short8*)&Ks[strow + 32][stcol] = kr1;
        *(short8*)&Vt[strow][stcol]      = vr0;
        *(short8*)&Vt[strow + 32][stcol] = vr1;
        __syncthreads();

        const int ktn = (kt + 64 < SEQ) ? kt + 64 : 0;
        kr0 = *(const short8*)&kg0[(size_t)ktn * DK];
        kr1 = *(const short8*)&kg1[(size_t)ktn * DK];
        vr0 = *(const short8*)&vg0[ktn];
        vr1 = *(const short8*)&vg1[ktn];

        // ---- S^T = K Q^T : C[row=key scatter][col=m=lane&31], 4 MFMAs ----
        floatx16 sc = (floatx16)(0.f);
#pragma unroll
        for (int t = 0; t < 4; ++t) {
            const short8 kf = *(short8*)&Ks[kb + l31][t * 16 + lh * 8];
            sc = __builtin_amdgcn_mfma_f32_32x32x16_bf16(kf, qf[t], sc, 0, 0, 0);
        }

        // ---- diagonal mask: only diag tile, only waves with kh==mh ----
        if (kt == diag_kt && kh == mh) {
#pragma unroll
            for (int r = 0; r < 16; ++r) {
                const int key_loc = (r & 3) + 8 * (r >> 2) + 4 * lh;
                if (key_loc == l31) sc[r] = -1e30f;
            }
        }

        // ---- P = exp2(S^T): native v_exp_f32 + v_perm trunc pack; lp accumulates ----
        short8 pf0, pf1;
        {
            union { unsigned int u[4]; short8 s8; } a, c;
#pragma unroll
            for (int d = 0; d < 4; ++d) {
                const float e0 = __builtin_amdgcn_exp2f(sc[2 * d]);
                const float e1 = __builtin_amdgcn_exp2f(sc[2 * d + 1]);
                a.u[d] = __builtin_amdgcn_perm(fau(e1), fau(e0), 0x07060302u);
                const float f0 = __builtin_amdgcn_exp2f(sc[8 + 2 * d]);
                const float f1 = __builtin_amdgcn_exp2f(sc[8 + 2 * d + 1]);
                c.u[d] = __builtin_amdgcn_perm(fau(f1), fau(f0), 0x07060302u);
                lp += (e0 + e1) + (f0 + f1);
            }
            pf0 = a.s8;
            pf1 = c.s8;
        }

        // ---- O += P V  (V pre-permuted so k-indices align) ----
#pragma unroll
        for (int nd = 0; nd < 2; ++nd) {
            const short8 vfa = *(short8*)&Vt[nd * 32 + l31][kb + lh * 8];        // keys 0..15
            const short8 vfb = *(short8*)&Vt[nd * 32 + l31][kb + 16 + lh * 8];   // keys 16..31
            oacc[nd] = __builtin_amdgcn_mfma_f32_32x32x16_bf16(pf0, vfa, oacc[nd], 0, 0, 0);
            oacc[nd] = __builtin_amdgcn_mfma_f32_32x32x16_bf16(pf1, vfb, oacc[nd], 0, 0, 0);
        }
    }

    // ---- l: combine the two lane-halves (same m, disjoint keys) ----
    const float lptot = lp + __shfl_xor(lp, 32, 64);

    // ---- cross-wave (key-half) reduction through LDS overlay ----
    __syncthreads();                          // Ks/Vt dead
    if (lh == 0) {
        if (kh == 0) lred0[mh * 32 + l31] = lptot;
        else         lred1[mh * 32 + l31] = lptot;
    }
    if (kh == 1) {
#pragma unroll
        for (int r = 0; r < 16; ++r) {
            const int m = mh * 32 + (r & 3) + 8 * (r >> 2) + 4 * lh;
            Ored[m][l31]      = oacc[0][r];
            Ored[m][32 + l31] = oacc[1][r];
        }
    }
    __syncthreads();
    if (kh == 0) {
        unsigned short* obase = attnb + ((size_t)b * SEQ + (size_t)qt * QTILE) * D_MODEL + h * DK;
        // 1.001953125 = 1/(1 - 2^-9): compensates mean truncation bias of bf16 P
        // (numerator uses trunc(P), denominator uses full-precision sums).
#pragma unroll
        for (int r = 0; r < 16; ++r) {
            const int m = mh * 32 + (r & 3) + 8 * (r >> 2) + 4 * lh;
            const float inv = 1.001953125f / (lred0[m] + lred1[m]);
            const float v0 = (oacc[0][r] + Ored[m][l31]) * inv;
            const float v1 = (oacc[1][r] + Ored[m][32 + l31]) * inv;
            obase[(size_t)m * D_MODEL + l31]      = f2bf(v0);
            obase[(size_t)m * D_MODEL + 32 + l31] = f2bf(v1);
        }
    }
}

extern "C" void kernel_launch(void* const* d_in, const int* in_sizes, int n_in,
                              void* d_out, int out_size, void* d_ws, size_t ws_size,
                              hipStream_t stream) {
    const float* x     = (const float*)d_in[0];
    const float* w_qkv = (const float*)d_in[1];
    const float* w_out = (const float*)d_in[2];
    const float* b_out = (const float*)d_in[3];
    float* out = (float*)d_out;

    const int M = BATCH * SEQ;                                   // 4096
    const size_t X_ELEMS    = (size_t)M * D_MODEL;
    const size_t WQKV_ELEMS = (size_t)3 * D_MODEL * D_MODEL;
    const size_t WOUT_ELEMS = (size_t)D_MODEL * D_MODEL;
    const size_t QKV_ELEMS  = (size_t)M * 3 * D_MODEL;
    const size_t HEAD_ELEMS = (size_t)BATCH * NHEADS * SEQ * DK;

    unsigned short* xb    = (unsigned short*)d_ws;
    unsigned short* wqkvb = xb + X_ELEMS;
    unsigned short* woutb = wqkvb + WQKV_ELEMS;
    unsigned short* qkvb  = woutb + WOUT_ELEMS;
    unsigned short* Qb    = qkvb + QKV_ELEMS;
    unsigned short* Kb    = Qb + HEAD_ELEMS;
    unsigned short* Vtg   = Kb + HEAD_ELEMS;                     // [B,H,64,S] sigma-permuted
    unsigned short* attnb = Vtg + HEAD_ELEMS;

    // 0) pack all inputs to bf16
    pack_all<<<(X8 + W8 + O8 + 255) / 256, 256, 0, stream>>>(x, w_qkv, w_out, xb, wqkvb, woutb);

    // 1) qkvb = xb @ wqkvb^T
    {
        dim3 grid(3 * D_MODEL / 128, M / 128);
        gemm_bf16<128, unsigned short><<<grid, 256, 0, stream>>>(xb, wqkvb, nullptr, qkvb,
                                                                 M, 3 * D_MODEL, D_MODEL);
    }
    // 2) RoPE pack + sigma-permuted V transpose
    {
        dim3 grid(SEQ / 64, NHEADS, BATCH);
        rope_vtrans<<<grid, 256, 0, stream>>>(qkvb, Qb, Kb, Vtg);
    }
    // 3) flash attention (32x32 MFMA, register P, scalar l)
    {
        dim3 grid(SEQ / QTILE, NHEADS, BATCH);
        flash_attn<<<grid, 256, 0, stream>>>(Qb, Kb, Vtg, attnb);
    }
    // 4) out = attnb @ woutb^T + b_out
    {
        dim3 grid(D_MODEL / 128, M / 64);
        gemm_bf16<64, float><<<grid, 256, 0, stream>>>(attnb, woutb, b_out, out,
                                                       M, D_MODEL, D_MODEL);
    }
}